// Round 12
// baseline (427.513 us; speedup 1.0000x reference)
//
#include <hip/hip_runtime.h>
#include <hip/hip_bf16.h>

// Problem constants
#define HH 256
#define WW 256
#define CCH 1024
#define PP 1024   // 32*32 patches per image

using f32x4 = __attribute__((ext_vector_type(4))) float;
using short8 = __attribute__((ext_vector_type(8))) short;

// ---------------------------------------------------------------------------
// pool_direct: patch pool writing yT bf16 directly (no y, no transpose).
// job = ph*32 + cc: block computes patches (ph, pw=0..31) for 32 planes
// c = cc*32..cc*32+31.  Wave w reduces 8 planes (full 8x256 slab each, plain
// f32x4 row reads, shfl_xor(1) pair-reduce) -> LDS[pw][c_local]; writeback as
// short8 (16B), 64B cross-block granularity (R5-proven replay-safe).
// ---------------------------------------------------------------------------
__device__ __forceinline__ void pool_direct_body(const float* __restrict__ xb,
                                                 __hip_bfloat16* __restrict__ yTb,
                                                 int job, int t) {
    __shared__ float lds[32][33];
    int ph = job >> 5, c0 = (job & 31) * 32;
    int wid = t >> 6, lane = t & 63;
#pragma unroll 2
    for (int i = 0; i < 8; ++i) {
        int cl = wid * 8 + i;
        const float* base = xb + (size_t)(c0 + cl) * (HH * WW)
                          + (size_t)ph * 8 * WW + lane * 4;
        float acc = 0.f;
#pragma unroll
        for (int r = 0; r < 8; ++r) {
            f32x4 v = *(const f32x4*)(base + r * WW);
            acc += v.x + v.y + v.z + v.w;
        }
        acc += __shfl_xor(acc, 1);
        if ((lane & 1) == 0)
            lds[lane >> 1][cl] = acc * (1.f / 64.f);
    }
    __syncthreads();
    if (t < 128) {
        int row = t >> 2, q = t & 3;
        short8 s;
#pragma unroll
        for (int j = 0; j < 8; ++j) {
            __hip_bfloat16 h = __float2bfloat16(lds[row][q * 8 + j]);
            s[j] = (short)reinterpret_cast<unsigned short&>(h);
        }
        *(short8*)(yTb + (size_t)(1 + ph * 32 + row) * CCH + c0 + q * 8) = s;
    }
}

// ---------------------------------------------------------------------------
// gemm body (R1/R9-proven): block = 64(co) x 32(p), 4 waves along co, wave
// tile 16x32.  job = by*16 + bx over grid 16x32.
// ---------------------------------------------------------------------------
__device__ __forceinline__ void gemm_body(const __hip_bfloat16* __restrict__ wT,
                                          const __hip_bfloat16* __restrict__ yTb,
                                          float* __restrict__ gateb,
                                          int job, int tid) {
    int lane = tid & 63;
    int wid  = tid >> 6;
    int l15 = lane & 15, lhi = lane >> 4;
    int co_base = (job & 15) * 64 + wid * 16;
    int p_base  = (job >> 4) * 32;
    f32x4 acc[2] = {};
#pragma unroll
    for (int tap = 0; tap < 3; ++tap) {
        const __hip_bfloat16* Ap = wT + (size_t)tap * (1u << 20)
                                 + (size_t)(co_base + l15) * CCH + lhi * 8;
        const __hip_bfloat16* Bp = yTb + (size_t)(p_base + l15 + tap) * CCH + lhi * 8;
        for (int ci0 = 0; ci0 < CCH; ci0 += 32) {
            short8 a0 = *(const short8*)(Ap + ci0);
            short8 b0 = *(const short8*)(Bp + ci0);
            short8 b1 = *(const short8*)(Bp + ci0 + 16 * CCH);
            acc[0] = __builtin_amdgcn_mfma_f32_16x16x32_bf16(a0, b0, acc[0], 0, 0, 0);
            acc[1] = __builtin_amdgcn_mfma_f32_16x16x32_bf16(a0, b1, acc[1], 0, 0, 0);
        }
    }
    // C/D layout: col = lane&15, row = (lane>>4)*4 + reg  [m89/m91].
#pragma unroll
    for (int j16 = 0; j16 < 2; ++j16) {
        int col  = p_base + j16 * 16 + l15;
        int row0 = co_base + lhi * 4;
#pragma unroll
        for (int r = 0; r < 4; ++r)
            gateb[(size_t)(row0 + r) * PP + col] = 1.f / (1.f + __expf(-acc[j16][r]));
    }
}

// ---------------------------------------------------------------------------
// apply body: PURE STREAM — no LDS, no barrier.  Thread owns (f32x4 col-chunk,
// row-group r in 0..3); 32 strips of 8 rows; per strip one scalar gate load
// (L2-resident, hoisted across unroll-8), then 2 independent load->mul->NT
// store pairs.  Matches the copy-ubench structure.
// ---------------------------------------------------------------------------
__device__ __forceinline__ void apply_body(const float* __restrict__ xb,
                                           const float* __restrict__ gateb,
                                           float* __restrict__ outb,
                                           int c, int t) {
    const float* xp = xb   + (size_t)c * (HH * WW);
    float*       op = outb + (size_t)c * (HH * WW);
    int col4 = t & 63;                    // f32x4 column chunk 0..63
    int r    = t >> 6;                    // row-group 0..3
    int pc   = col4 >> 1;                 // patch column 0..31
    const float* grow = gateb + (size_t)c * PP + pc;
#pragma unroll 8
    for (int s = 0; s < 32; ++s) {
        float gg = grow[s * 32];
#pragma unroll
        for (int ss = 0; ss < 2; ++ss) {
            int row = s * 8 + ss * 4 + r;
            size_t off = (size_t)row * 64 + col4;   // f32x4 units
            f32x4 v = *((const f32x4*)xp + off);
            v *= gg;
            __builtin_nontemporal_store(v, (f32x4*)op + off);
        }
    }
}

// ---------------------------------------------------------------------------
// L1: pool_direct(b0) [blocks 0..1023] ∥ wconv+pad [blocks 1024..1279].
// ---------------------------------------------------------------------------
__global__ __launch_bounds__(256) void pool0_wconv_kernel(
        const float* __restrict__ x, const float* __restrict__ w,
        __hip_bfloat16* __restrict__ yT, __hip_bfloat16* __restrict__ wT) {
    int bid = blockIdx.x, t = threadIdx.x;
    if (bid < 1024) {
        pool_direct_body(x, yT, bid, t);
    } else {
        int base = (bid - 1024) * 256 + t;       // 0..65535
#pragma unroll
        for (int it = 0; it < 16; ++it) {
            int idx = it * (1 << 16) + base;     // co*1024+ci
            const float* p = w + (size_t)idx * 3;
            wT[idx]               = __float2bfloat16(p[0]);
            wT[(1u << 20) + idx]  = __float2bfloat16(p[1]);
            wT[(2u << 20) + idx]  = __float2bfloat16(p[2]);
        }
        if (base < 2 * CCH) {
            int bb = base >> 10, cc = base & 1023;
            __hip_bfloat16 z = __float2bfloat16(0.f);
            __hip_bfloat16* basep = yT + (size_t)bb * (PP + 2) * CCH;
            basep[cc] = z;
            basep[(size_t)(PP + 1) * CCH + cc] = z;
        }
    }
}

// ---------------------------------------------------------------------------
// L2: gemm0 [blocks 0..511, starts immediately] ∥ pool_direct(b1) [512..1535].
// ---------------------------------------------------------------------------
__global__ __launch_bounds__(256) void gemm0_pool1_kernel(
        const float* __restrict__ x, const __hip_bfloat16* __restrict__ wT,
        __hip_bfloat16* __restrict__ yT, float* __restrict__ gate) {
    int bid = blockIdx.x, t = threadIdx.x;
    if (bid < 512) {
        gemm_body(wT, yT, gate, bid, t);
    } else {
        const float* x1 = x + (size_t)CCH * HH * WW;
        __hip_bfloat16* yT1 = yT + (size_t)(PP + 2) * CCH;
        pool_direct_body(x1, yT1, bid - 512, t);
    }
}

// ---------------------------------------------------------------------------
// L3: gemm1 [blocks 0..511] ∥ apply0 [512..1535, reversed planes].
// ---------------------------------------------------------------------------
__global__ __launch_bounds__(256) void gemm1_apply0_kernel(
        const float* __restrict__ x, const __hip_bfloat16* __restrict__ wT,
        const __hip_bfloat16* __restrict__ yT, float* __restrict__ gate,
        float* __restrict__ out) {
    int bid = blockIdx.x, t = threadIdx.x;
    if (bid < 512) {
        const __hip_bfloat16* yT1 = yT + (size_t)(PP + 2) * CCH;
        float* gate1 = gate + (size_t)CCH * PP;
        gemm_body(wT, yT1, gate1, bid, t);
    } else {
        apply_body(x, gate, out, 1023 - (bid - 512), t);
    }
}

// ---------------------------------------------------------------------------
// L4: apply1 (reversed planes).
// ---------------------------------------------------------------------------
__global__ __launch_bounds__(256) void apply1_kernel(
        const float* __restrict__ x, const float* __restrict__ gate,
        float* __restrict__ out) {
    const float* x1    = x    + (size_t)CCH * HH * WW;
    const float* gate1 = gate + (size_t)CCH * PP;
    float*       out1  = out  + (size_t)CCH * HH * WW;
    apply_body(x1, gate1, out1, 1023 - blockIdx.x, threadIdx.x);
}

extern "C" void kernel_launch(void* const* d_in, const int* in_sizes, int n_in,
                              void* d_out, int out_size, void* d_ws, size_t ws_size,
                              hipStream_t stream) {
    const float* x = (const float*)d_in[0];       // [2,1024,256,256] f32
    const float* w = (const float*)d_in[1];       // [1024,1024,3] f32
    float* out = (float*)d_out;                   // [2,1024,256,256] f32

    // Workspace layout (256-aligned):
    //   yT   bf16 [2][1026][1024]   4,202,496 B @ 0
    //   wT   bf16 [3][1024][1024]   6,291,456 B @  4,202,496
    //   gate f32  [2][1024][1024]   8,388,608 B @ 10,493,952   (tot ~18.9 MiB)
    char* ws = (char*)d_ws;
    __hip_bfloat16* yT   = (__hip_bfloat16*)(ws);
    __hip_bfloat16* wT   = (__hip_bfloat16*)(ws + 4202496);
    float*          gate = (float*)(ws + 10493952);

    hipLaunchKernelGGL(pool0_wconv_kernel, dim3(1280), dim3(256), 0, stream,
                       x, w, yT, wT);
    hipLaunchKernelGGL(gemm0_pool1_kernel, dim3(1536), dim3(256), 0, stream,
                       x, wT, yT, gate);
    hipLaunchKernelGGL(gemm1_apply0_kernel, dim3(1536), dim3(256), 0, stream,
                       x, wT, yT, gate, out);
    hipLaunchKernelGGL(apply1_kernel, dim3(1024), dim3(256), 0, stream,
                       x, gate, out);
}

// Round 13
// 415.855 us; speedup vs baseline: 1.0280x; 1.0280x over previous
//
#include <hip/hip_runtime.h>
#include <hip/hip_bf16.h>

// Problem constants
#define HH 256
#define WW 256
#define CCH 1024
#define PP 1024   // 32*32 patches per image

using f32x4 = __attribute__((ext_vector_type(4))) float;
using short8 = __attribute__((ext_vector_type(8))) short;

// ---------------------------------------------------------------------------
// pool_direct: patch pool writing yT bf16 directly (no y, no transpose).
// job = ph*32 + cc: block computes patches (ph, pw=0..31) for 32 planes
// c = cc*32..cc*32+31.  Wave w reduces 8 planes (full 8x256 slab each, NT
// f32x4 row reads, shfl_xor(1) pair-reduce) -> LDS[pw][c_local]; writeback as
// short8 (16B), 64B cross-block granularity (R5-proven replay-safe).
// ---------------------------------------------------------------------------
__device__ __forceinline__ void pool_direct_body(const float* __restrict__ xb,
                                                 __hip_bfloat16* __restrict__ yTb,
                                                 int job, int t) {
    __shared__ float lds[32][33];
    int ph = job >> 5, c0 = (job & 31) * 32;
    int wid = t >> 6, lane = t & 63;
#pragma unroll 2
    for (int i = 0; i < 8; ++i) {
        int cl = wid * 8 + i;
        const float* base = xb + (size_t)(c0 + cl) * (HH * WW)
                          + (size_t)ph * 8 * WW + lane * 4;
        float acc = 0.f;
#pragma unroll
        for (int r = 0; r < 8; ++r) {
            f32x4 v = __builtin_nontemporal_load((const f32x4*)(base + r * WW));
            acc += v.x + v.y + v.z + v.w;
        }
        acc += __shfl_xor(acc, 1);
        if ((lane & 1) == 0)
            lds[lane >> 1][cl] = acc * (1.f / 64.f);
    }
    __syncthreads();
    if (t < 128) {
        int row = t >> 2, q = t & 3;
        short8 s;
#pragma unroll
        for (int j = 0; j < 8; ++j) {
            __hip_bfloat16 h = __float2bfloat16(lds[row][q * 8 + j]);
            s[j] = (short)reinterpret_cast<unsigned short&>(h);
        }
        *(short8*)(yTb + (size_t)(1 + ph * 32 + row) * CCH + c0 + q * 8) = s;
    }
}

// ---------------------------------------------------------------------------
// gemm body (R1/R9-proven): block = 64(co) x 32(p), 4 waves along co, wave
// tile 16x32.  job = by*16 + bx over grid 16x32.
// ---------------------------------------------------------------------------
__device__ __forceinline__ void gemm_body(const __hip_bfloat16* __restrict__ wT,
                                          const __hip_bfloat16* __restrict__ yTb,
                                          float* __restrict__ gateb,
                                          int job, int tid) {
    int lane = tid & 63;
    int wid  = tid >> 6;
    int l15 = lane & 15, lhi = lane >> 4;
    int co_base = (job & 15) * 64 + wid * 16;
    int p_base  = (job >> 4) * 32;
    f32x4 acc[2] = {};
#pragma unroll
    for (int tap = 0; tap < 3; ++tap) {
        const __hip_bfloat16* Ap = wT + (size_t)tap * (1u << 20)
                                 + (size_t)(co_base + l15) * CCH + lhi * 8;
        const __hip_bfloat16* Bp = yTb + (size_t)(p_base + l15 + tap) * CCH + lhi * 8;
        for (int ci0 = 0; ci0 < CCH; ci0 += 32) {
            short8 a0 = *(const short8*)(Ap + ci0);
            short8 b0 = *(const short8*)(Bp + ci0);
            short8 b1 = *(const short8*)(Bp + ci0 + 16 * CCH);
            acc[0] = __builtin_amdgcn_mfma_f32_16x16x32_bf16(a0, b0, acc[0], 0, 0, 0);
            acc[1] = __builtin_amdgcn_mfma_f32_16x16x32_bf16(a0, b1, acc[1], 0, 0, 0);
        }
    }
    // C/D layout: col = lane&15, row = (lane>>4)*4 + reg  [m89/m91].
#pragma unroll
    for (int j16 = 0; j16 < 2; ++j16) {
        int col  = p_base + j16 * 16 + l15;
        int row0 = co_base + lhi * 4;
#pragma unroll
        for (int r = 0; r < 4; ++r)
            gateb[(size_t)(row0 + r) * PP + col] = 1.f / (1.f + __expf(-acc[j16][r]));
    }
}

// ---------------------------------------------------------------------------
// apply body (R10 structure): gate row (4KB) in LDS; wave covers a full
// 256-col row per iter.  NT loads on x; PLAIN stores on out (R13's single
// change vs R10 — let L2 merge 16B stores into full-line HBM writes).
// ---------------------------------------------------------------------------
__device__ __forceinline__ void apply_body(const float* __restrict__ xb,
                                           const float* __restrict__ gateb,
                                           float* __restrict__ outb,
                                           int c, int t) {
    __shared__ __align__(16) float g[PP];
    const float* xp = xb   + (size_t)c * (HH * WW);
    float*       op = outb + (size_t)c * (HH * WW);
    ((f32x4*)g)[t] = ((const f32x4*)(gateb + (size_t)c * PP))[t];
    __syncthreads();
    int col4 = t & 63;
    int r    = t >> 6;
    int pc   = col4 >> 1;
#pragma unroll 4
    for (int it = 0; it < 64; ++it) {
        int row = it * 4 + r;
        float gg = g[(row >> 3) * 32 + pc];
        size_t off = (size_t)row * 64 + col4;
        f32x4 v = __builtin_nontemporal_load((const f32x4*)xp + off);
        v *= gg;
        *((f32x4*)op + off) = v;     // plain store (was NT in R10)
    }
}

// ---------------------------------------------------------------------------
// L1: pool_direct(b0) [blocks 0..1023] ∥ wconv+pad [blocks 1024..1279].
// ---------------------------------------------------------------------------
__global__ __launch_bounds__(256) void pool0_wconv_kernel(
        const float* __restrict__ x, const float* __restrict__ w,
        __hip_bfloat16* __restrict__ yT, __hip_bfloat16* __restrict__ wT) {
    int bid = blockIdx.x, t = threadIdx.x;
    if (bid < 1024) {
        pool_direct_body(x, yT, bid, t);
    } else {
        int base = (bid - 1024) * 256 + t;       // 0..65535
#pragma unroll
        for (int it = 0; it < 16; ++it) {
            int idx = it * (1 << 16) + base;     // co*1024+ci
            const float* p = w + (size_t)idx * 3;
            wT[idx]               = __float2bfloat16(p[0]);
            wT[(1u << 20) + idx]  = __float2bfloat16(p[1]);
            wT[(2u << 20) + idx]  = __float2bfloat16(p[2]);
        }
        if (base < 2 * CCH) {
            int bb = base >> 10, cc = base & 1023;
            __hip_bfloat16 z = __float2bfloat16(0.f);
            __hip_bfloat16* basep = yT + (size_t)bb * (PP + 2) * CCH;
            basep[cc] = z;
            basep[(size_t)(PP + 1) * CCH + cc] = z;
        }
    }
}

// ---------------------------------------------------------------------------
// L2: gemm0 [blocks 0..511, starts immediately] ∥ pool_direct(b1) [512..1535].
// ---------------------------------------------------------------------------
__global__ __launch_bounds__(256) void gemm0_pool1_kernel(
        const float* __restrict__ x, const __hip_bfloat16* __restrict__ wT,
        __hip_bfloat16* __restrict__ yT, float* __restrict__ gate) {
    int bid = blockIdx.x, t = threadIdx.x;
    if (bid < 512) {
        gemm_body(wT, yT, gate, bid, t);
    } else {
        const float* x1 = x + (size_t)CCH * HH * WW;
        __hip_bfloat16* yT1 = yT + (size_t)(PP + 2) * CCH;
        pool_direct_body(x1, yT1, bid - 512, t);
    }
}

// ---------------------------------------------------------------------------
// L3: gemm1 [blocks 0..511] ∥ apply0 [512..1535, reversed planes].
// ---------------------------------------------------------------------------
__global__ __launch_bounds__(256) void gemm1_apply0_kernel(
        const float* __restrict__ x, const __hip_bfloat16* __restrict__ wT,
        const __hip_bfloat16* __restrict__ yT, float* __restrict__ gate,
        float* __restrict__ out) {
    int bid = blockIdx.x, t = threadIdx.x;
    if (bid < 512) {
        const __hip_bfloat16* yT1 = yT + (size_t)(PP + 2) * CCH;
        float* gate1 = gate + (size_t)CCH * PP;
        gemm_body(wT, yT1, gate1, bid, t);
    } else {
        apply_body(x, gate, out, 1023 - (bid - 512), t);
    }
}

// ---------------------------------------------------------------------------
// L4: apply1 (reversed planes).
// ---------------------------------------------------------------------------
__global__ __launch_bounds__(256) void apply1_kernel(
        const float* __restrict__ x, const float* __restrict__ gate,
        float* __restrict__ out) {
    const float* x1    = x    + (size_t)CCH * HH * WW;
    const float* gate1 = gate + (size_t)CCH * PP;
    float*       out1  = out  + (size_t)CCH * HH * WW;
    apply_body(x1, gate1, out1, 1023 - blockIdx.x, threadIdx.x);
}

extern "C" void kernel_launch(void* const* d_in, const int* in_sizes, int n_in,
                              void* d_out, int out_size, void* d_ws, size_t ws_size,
                              hipStream_t stream) {
    const float* x = (const float*)d_in[0];       // [2,1024,256,256] f32
    const float* w = (const float*)d_in[1];       // [1024,1024,3] f32
    float* out = (float*)d_out;                   // [2,1024,256,256] f32

    // Workspace layout (256-aligned):
    //   yT   bf16 [2][1026][1024]   4,202,496 B @ 0
    //   wT   bf16 [3][1024][1024]   6,291,456 B @  4,202,496
    //   gate f32  [2][1024][1024]   8,388,608 B @ 10,493,952   (tot ~18.9 MiB)
    char* ws = (char*)d_ws;
    __hip_bfloat16* yT   = (__hip_bfloat16*)(ws);
    __hip_bfloat16* wT   = (__hip_bfloat16*)(ws + 4202496);
    float*          gate = (float*)(ws + 10493952);

    hipLaunchKernelGGL(pool0_wconv_kernel, dim3(1280), dim3(256), 0, stream,
                       x, w, yT, wT);
    hipLaunchKernelGGL(gemm0_pool1_kernel, dim3(1536), dim3(256), 0, stream,
                       x, wT, yT, gate);
    hipLaunchKernelGGL(gemm1_apply0_kernel, dim3(1536), dim3(256), 0, stream,
                       x, wT, yT, gate, out);
    hipLaunchKernelGGL(apply1_kernel, dim3(1024), dim3(256), 0, stream,
                       x, gate, out);
}